// Round 1
// baseline (1743.640 us; speedup 1.0000x reference)
//
#include <hip/hip_runtime.h>
#include <math.h>

// ws layout (floats):
//   [0, 24576)     T tables [3][64][128]  (b0 folded into axis 0)
//   [24576, 40960) W1n [128][128] (weight-normed)
//   [40960, 41088) w2n [128] (weight-normed row * g2)

__global__ void precompute_T(const float* __restrict__ expr,
                             const float* __restrict__ jqw,
                             const float* __restrict__ flx,
                             const float* __restrict__ fly,
                             const float* __restrict__ flz,
                             const float* __restrict__ w0v,
                             const float* __restrict__ w0g,
                             const float* __restrict__ b0,
                             float* __restrict__ T) {
    int a = blockIdx.x >> 6;   // axis 0..2
    int l = blockIdx.x & 63;   // grid row 0..63
    const float* fl = (a == 0) ? flx : (a == 1) ? fly : flz;
    __shared__ float bs[32];
    __shared__ float jaw[32];
    int t = threadIdx.x;
    if (t < 32) {
        float s = 0.f;
        for (int i = 0; i < 80; ++i) s += expr[i] * fl[(i * 64 + l) * 32 + t];
        bs[t] = s;
    } else if (t < 64) {
        int c = t - 32;
        float s = 0.f;
        for (int i = 0; i < 16; ++i) s += jqw[i] * fl[((80 + i) * 64 + l) * 32 + c];
        jaw[c] = s;
    }
    __syncthreads();
    int j = t;  // 128 threads, one output channel each
    float ns = 0.f;
    for (int c = 0; c < 192; ++c) { float v = w0v[j * 192 + c]; ns += v * v; }
    float scale = w0g[j] / sqrtf(ns);
    float acc = 0.f;
    for (int c = 0; c < 32; ++c) acc += w0v[j * 192 + a * 32 + c] * bs[c];
    for (int c = 0; c < 32; ++c) acc += w0v[j * 192 + 96 + a * 32 + c] * jaw[c];
    acc *= scale;
    if (a == 0) acc += b0[j];
    T[(a * 64 + l) * 128 + j] = acc;
}

__global__ void precompute_W(const float* __restrict__ w1v,
                             const float* __restrict__ w1g,
                             const float* __restrict__ w2v,
                             const float* __restrict__ w2g,
                             float* __restrict__ W1n,
                             float* __restrict__ w2n) {
    int j = threadIdx.x;  // 128 threads
    float ns = 0.f;
    for (int k = 0; k < 128; ++k) { float v = w1v[j * 128 + k]; ns += v * v; }
    float s = w1g[j] / sqrtf(ns);
    for (int k = 0; k < 128; ++k) W1n[j * 128 + k] = w1v[j * 128 + k] * s;
    float n2 = 0.f;
    for (int k = 0; k < 128; ++k) { float v = w2v[k]; n2 += v * v; }
    w2n[j] = w2v[j] * (w2g[0] / sqrtf(n2));
}

#define T_QUADS 6144   // 3*64*32 float4 quads
#define W1_QUADS 4096  // 128*128/4
#define W1_OFF 24576   // float offset of W1 in LDS

__launch_bounds__(512, 2)
__global__ void mlp_main(const float* __restrict__ xyz,
                         const float* __restrict__ Tg,
                         const float* __restrict__ W1g,
                         const float* __restrict__ w2ng,
                         const float* __restrict__ b1,
                         const float* __restrict__ b2p,
                         float* __restrict__ out, int npts) {
    __shared__ __align__(16) float lds[40960];  // exactly 160 KiB
    int tid = threadIdx.x;

    // Stage T with per-row XOR swizzle on 16B quads: logical quad q of row l
    // lands at physical quad (q ^ (l&31)). Spreads the data-dependent row
    // gather (uniform q, random l per lane) across bank-quads.
    for (int u = tid; u < T_QUADS; u += 512) {
        int q = u & 31;
        int l = (u >> 5) & 63;
        float4 v = reinterpret_cast<const float4*>(Tg)[u];
        int phys = (u & ~31) | (q ^ (l & 31));
        reinterpret_cast<float4*>(lds)[phys] = v;
    }
    // Stage W1 linear (read uniformly later -> broadcast, no conflicts)
    for (int u = tid; u < W1_QUADS; u += 512) {
        reinterpret_cast<float4*>(lds + W1_OFF)[u] =
            reinterpret_cast<const float4*>(W1g)[u];
    }
    __syncthreads();

    float b2 = b2p[0];
    int stride = 512 * gridDim.x;
#pragma unroll 1
    for (int idx = blockIdx.x * 512 + tid; idx < npts; idx += stride) {
        float px = xyz[idx * 3 + 0];
        float py = xyz[idx * 3 + 1];
        float pz = xyz[idx * 3 + 2];

        float h0[128];
#pragma unroll
        for (int j = 0; j < 128; ++j) h0[j] = 0.f;

#pragma unroll
        for (int a = 0; a < 3; ++a) {
            float v = (a == 0) ? px : (a == 1) ? py : pz;
            v = fminf(fmaxf(v, 0.f), 1.f) * 63.f;
            float fl = floorf(v);
            int li = (int)fl;
            int ri = min(li + 1, 63);
            float w = v - fl;
            float wl = 1.f - w;
            int baseL = (a * 64 + li) * 32;
            int baseR = (a * 64 + ri) * 32;
            int sl = li & 31;
            int sr = ri & 31;
#pragma unroll
            for (int q = 0; q < 32; ++q) {
                float4 vl = reinterpret_cast<float4*>(lds)[baseL + (q ^ sl)];
                float4 vr = reinterpret_cast<float4*>(lds)[baseR + (q ^ sr)];
                h0[q * 4 + 0] += wl * vl.x + w * vr.x;
                h0[q * 4 + 1] += wl * vl.y + w * vr.y;
                h0[q * 4 + 2] += wl * vl.z + w * vr.z;
                h0[q * 4 + 3] += wl * vl.w + w * vr.w;
            }
        }
#pragma unroll
        for (int j = 0; j < 128; ++j) h0[j] = fmaxf(h0[j], 0.f);

        float acc = b2;
#pragma unroll 1
        for (int jo = 0; jo < 128; jo += 8) {
            float s[8];
#pragma unroll
            for (int jj = 0; jj < 8; ++jj) s[jj] = b1[jo + jj];
#pragma unroll
            for (int kq = 0; kq < 32; ++kq) {
#pragma unroll
                for (int jj = 0; jj < 8; ++jj) {
                    float4 wv =
                        reinterpret_cast<float4*>(lds + W1_OFF)[(jo + jj) * 32 + kq];
                    s[jj] += wv.x * h0[kq * 4 + 0];
                    s[jj] += wv.y * h0[kq * 4 + 1];
                    s[jj] += wv.z * h0[kq * 4 + 2];
                    s[jj] += wv.w * h0[kq * 4 + 3];
                }
            }
#pragma unroll
            for (int jj = 0; jj < 8; ++jj)
                acc += w2ng[jo + jj] * fmaxf(s[jj], 0.f);
        }
        out[idx] = acc;
    }
}

extern "C" void kernel_launch(void* const* d_in, const int* in_sizes, int n_in,
                              void* d_out, int out_size, void* d_ws, size_t ws_size,
                              hipStream_t stream) {
    const float* expr = (const float*)d_in[0];
    const float* jqw  = (const float*)d_in[1];
    const float* xyz  = (const float*)d_in[2];
    const float* flx  = (const float*)d_in[3];
    const float* fly  = (const float*)d_in[4];
    const float* flz  = (const float*)d_in[5];
    const float* w0v  = (const float*)d_in[6];
    const float* w0g  = (const float*)d_in[7];
    const float* b0   = (const float*)d_in[8];
    const float* w1v  = (const float*)d_in[9];
    const float* w1g  = (const float*)d_in[10];
    const float* b1   = (const float*)d_in[11];
    const float* w2v  = (const float*)d_in[12];
    const float* w2g  = (const float*)d_in[13];
    const float* b2   = (const float*)d_in[14];

    float* ws = (float*)d_ws;
    float* T   = ws;            // 24576 floats
    float* W1n = ws + 24576;    // 16384 floats
    float* w2n = ws + 40960;    // 128 floats

    int npts = in_sizes[2] / 3;

    precompute_T<<<192, 128, 0, stream>>>(expr, jqw, flx, fly, flz, w0v, w0g, b0, T);
    precompute_W<<<1, 128, 0, stream>>>(w1v, w1g, w2v, w2g, W1n, w2n);
    mlp_main<<<512, 512, 0, stream>>>(xyz, T, W1n, w2n, b1, b2, (float*)d_out, npts);
}

// Round 3
// 1743.145 us; speedup vs baseline: 1.0003x; 1.0003x over previous
//
#include <hip/hip_runtime.h>
#include <math.h>

// ws layout (floats):
//   [0, 24576)     T tables [3][64][128]  (b0 folded into axis 0)
//   [24576, 40960) W1n [128][128] (weight-normed)
//   [40960, 41088) w2n [128] (weight-normed row * g2)

__global__ void precompute_T(const float* __restrict__ expr,
                             const float* __restrict__ jqw,
                             const float* __restrict__ flx,
                             const float* __restrict__ fly,
                             const float* __restrict__ flz,
                             const float* __restrict__ w0v,
                             const float* __restrict__ w0g,
                             const float* __restrict__ b0,
                             float* __restrict__ T) {
    int a = blockIdx.x >> 6;   // axis 0..2
    int l = blockIdx.x & 63;   // grid row 0..63
    const float* fl = (a == 0) ? flx : (a == 1) ? fly : flz;
    __shared__ float bs[32];
    __shared__ float jaw[32];
    int t = threadIdx.x;
    if (t < 32) {
        float s = 0.f;
        for (int i = 0; i < 80; ++i) s += expr[i] * fl[(i * 64 + l) * 32 + t];
        bs[t] = s;
    } else if (t < 64) {
        int c = t - 32;
        float s = 0.f;
        for (int i = 0; i < 16; ++i) s += jqw[i] * fl[((80 + i) * 64 + l) * 32 + c];
        jaw[c] = s;
    }
    __syncthreads();
    int j = t;  // 128 threads, one output channel each
    float ns = 0.f;
    for (int c = 0; c < 192; ++c) { float v = w0v[j * 192 + c]; ns += v * v; }
    float scale = w0g[j] / sqrtf(ns);
    float acc = 0.f;
    for (int c = 0; c < 32; ++c) acc += w0v[j * 192 + a * 32 + c] * bs[c];
    for (int c = 0; c < 32; ++c) acc += w0v[j * 192 + 96 + a * 32 + c] * jaw[c];
    acc *= scale;
    if (a == 0) acc += b0[j];
    T[(a * 64 + l) * 128 + j] = acc;
}

__global__ void precompute_W(const float* __restrict__ w1v,
                             const float* __restrict__ w1g,
                             const float* __restrict__ w2v,
                             const float* __restrict__ w2g,
                             float* __restrict__ W1n,
                             float* __restrict__ w2n) {
    int j = threadIdx.x;  // 128 threads
    float ns = 0.f;
    for (int k = 0; k < 128; ++k) { float v = w1v[j * 128 + k]; ns += v * v; }
    float s = w1g[j] / sqrtf(ns);
    for (int k = 0; k < 128; ++k) W1n[j * 128 + k] = w1v[j * 128 + k] * s;
    float n2 = 0.f;
    for (int k = 0; k < 128; ++k) { float v = w2v[k]; n2 += v * v; }
    w2n[j] = w2v[j] * (w2g[0] / sqrtf(n2));
}

#define T_QUADS 6144   // 3*64*32 float4 quads
#define W1_QUADS 4096  // 128*128/4
#define W1_OFF 24576   // float offset of W1 in LDS

// 1 block/CU (LDS=160KB forces this anyway) -> 256-VGPR cap, no h0 spill.
__launch_bounds__(512, 1)
__global__ void mlp_main(const float* __restrict__ xyz,
                         const float* __restrict__ Tg,
                         const float* __restrict__ W1g,
                         const float* __restrict__ w2ng,
                         const float* __restrict__ b1,
                         const float* __restrict__ b2p,
                         float* __restrict__ out, int npts) {
    __shared__ __align__(16) float lds[40960];  // exactly 160 KiB
    int tid = threadIdx.x;

    // Stage T with per-row XOR swizzle on 16B quads: logical quad q of row l
    // lands at physical quad (q ^ (l&31)). Spreads the data-dependent row
    // gather (uniform q, random l per lane) across bank-quads.
    for (int u = tid; u < T_QUADS; u += 512) {
        int q = u & 31;
        int l = (u >> 5) & 63;
        float4 v = reinterpret_cast<const float4*>(Tg)[u];
        int phys = (u & ~31) | (q ^ (l & 31));
        reinterpret_cast<float4*>(lds)[phys] = v;
    }
    // Stage W1 linear (read uniformly later -> broadcast, no conflicts)
    for (int u = tid; u < W1_QUADS; u += 512) {
        reinterpret_cast<float4*>(lds + W1_OFF)[u] =
            reinterpret_cast<const float4*>(W1g)[u];
    }
    __syncthreads();

    float b2 = b2p[0];
    int stride = 512 * gridDim.x;
#pragma unroll 1
    for (int idx = blockIdx.x * 512 + tid; idx < npts; idx += stride) {
        float px = xyz[idx * 3 + 0];
        float py = xyz[idx * 3 + 1];
        float pz = xyz[idx * 3 + 2];

        float h0[128];
#pragma unroll
        for (int j = 0; j < 128; ++j) h0[j] = 0.f;

#pragma unroll
        for (int a = 0; a < 3; ++a) {
            float v = (a == 0) ? px : (a == 1) ? py : pz;
            v = fminf(fmaxf(v, 0.f), 1.f) * 63.f;
            float fl = floorf(v);
            int li = (int)fl;
            int ri = min(li + 1, 63);
            float w = v - fl;
            float wl = 1.f - w;
            int baseL = (a * 64 + li) * 32;
            int baseR = (a * 64 + ri) * 32;
            int sl = li & 31;
            int sr = ri & 31;
#pragma unroll
            for (int q = 0; q < 32; ++q) {
                float4 vl = reinterpret_cast<float4*>(lds)[baseL + (q ^ sl)];
                float4 vr = reinterpret_cast<float4*>(lds)[baseR + (q ^ sr)];
                h0[q * 4 + 0] += wl * vl.x + w * vr.x;
                h0[q * 4 + 1] += wl * vl.y + w * vr.y;
                h0[q * 4 + 2] += wl * vl.z + w * vr.z;
                h0[q * 4 + 3] += wl * vl.w + w * vr.w;
            }
        }
#pragma unroll
        for (int j = 0; j < 128; ++j) h0[j] = fmaxf(h0[j], 0.f);

        float acc = b2;
#pragma unroll 1
        for (int jo = 0; jo < 128; jo += 8) {
            float s[8];
#pragma unroll
            for (int jj = 0; jj < 8; ++jj) s[jj] = b1[jo + jj];
#pragma unroll
            for (int kq = 0; kq < 32; ++kq) {
#pragma unroll
                for (int jj = 0; jj < 8; ++jj) {
                    float4 wv =
                        reinterpret_cast<float4*>(lds + W1_OFF)[(jo + jj) * 32 + kq];
                    s[jj] += wv.x * h0[kq * 4 + 0];
                    s[jj] += wv.y * h0[kq * 4 + 1];
                    s[jj] += wv.z * h0[kq * 4 + 2];
                    s[jj] += wv.w * h0[kq * 4 + 3];
                }
            }
#pragma unroll
            for (int jj = 0; jj < 8; ++jj)
                acc += w2ng[jo + jj] * fmaxf(s[jj], 0.f);
        }
        out[idx] = acc;
    }
}

extern "C" void kernel_launch(void* const* d_in, const int* in_sizes, int n_in,
                              void* d_out, int out_size, void* d_ws, size_t ws_size,
                              hipStream_t stream) {
    const float* expr = (const float*)d_in[0];
    const float* jqw  = (const float*)d_in[1];
    const float* xyz  = (const float*)d_in[2];
    const float* flx  = (const float*)d_in[3];
    const float* fly  = (const float*)d_in[4];
    const float* flz  = (const float*)d_in[5];
    const float* w0v  = (const float*)d_in[6];
    const float* w0g  = (const float*)d_in[7];
    const float* b0   = (const float*)d_in[8];
    const float* w1v  = (const float*)d_in[9];
    const float* w1g  = (const float*)d_in[10];
    const float* b1   = (const float*)d_in[11];
    const float* w2v  = (const float*)d_in[12];
    const float* w2g  = (const float*)d_in[13];
    const float* b2   = (const float*)d_in[14];

    float* ws = (float*)d_ws;
    float* T   = ws;            // 24576 floats
    float* W1n = ws + 24576;    // 16384 floats
    float* w2n = ws + 40960;    // 128 floats

    int npts = in_sizes[2] / 3;

    precompute_T<<<192, 128, 0, stream>>>(expr, jqw, flx, fly, flz, w0v, w0g, b0, T);
    precompute_W<<<1, 128, 0, stream>>>(w1v, w1g, w2v, w2g, W1n, w2n);
    mlp_main<<<512, 512, 0, stream>>>(xyz, T, W1n, w2n, b1, b2, (float*)d_out, npts);
}

// Round 4
// 789.319 us; speedup vs baseline: 2.2090x; 2.2084x over previous
//
#include <hip/hip_runtime.h>
#include <math.h>

typedef _Float16 h2 __attribute__((ext_vector_type(2)));

#if __has_builtin(__builtin_amdgcn_fdot2)
#define DOT2(a, b, c) __builtin_amdgcn_fdot2((a), (b), (c), false)
#else
static __device__ __forceinline__ float DOT2(h2 a, h2 b, float c) {
    return c + (float)a.x * (float)b.x + (float)a.y * (float)b.y;
}
#endif

// ws layout (floats):
//   [0, 24576)     T tables [3][64][128] f32 (b0 folded into axis 0)
//   [24576, 40960) W1n [128][128] f32 (weight-normed)
//   [40960, 41088) w2n [128] f32 (weight-normed row * g2)

__global__ void precompute_T(const float* __restrict__ expr,
                             const float* __restrict__ jqw,
                             const float* __restrict__ flx,
                             const float* __restrict__ fly,
                             const float* __restrict__ flz,
                             const float* __restrict__ w0v,
                             const float* __restrict__ w0g,
                             const float* __restrict__ b0,
                             float* __restrict__ T) {
    int a = blockIdx.x >> 6;   // axis 0..2
    int l = blockIdx.x & 63;   // grid row 0..63
    const float* fl = (a == 0) ? flx : (a == 1) ? fly : flz;
    __shared__ float bs[32];
    __shared__ float jaw[32];
    int t = threadIdx.x;
    if (t < 32) {
        float s = 0.f;
        for (int i = 0; i < 80; ++i) s += expr[i] * fl[(i * 64 + l) * 32 + t];
        bs[t] = s;
    } else if (t < 64) {
        int c = t - 32;
        float s = 0.f;
        for (int i = 0; i < 16; ++i) s += jqw[i] * fl[((80 + i) * 64 + l) * 32 + c];
        jaw[c] = s;
    }
    __syncthreads();
    int j = t;  // 128 threads, one output channel each
    float ns = 0.f;
    for (int c = 0; c < 192; ++c) { float v = w0v[j * 192 + c]; ns += v * v; }
    float scale = w0g[j] / sqrtf(ns);
    float acc = 0.f;
    for (int c = 0; c < 32; ++c) acc += w0v[j * 192 + a * 32 + c] * bs[c];
    for (int c = 0; c < 32; ++c) acc += w0v[j * 192 + 96 + a * 32 + c] * jaw[c];
    acc *= scale;
    if (a == 0) acc += b0[j];
    T[(a * 64 + l) * 128 + j] = acc;
}

__global__ void precompute_W(const float* __restrict__ w1v,
                             const float* __restrict__ w1g,
                             const float* __restrict__ w2v,
                             const float* __restrict__ w2g,
                             float* __restrict__ W1n,
                             float* __restrict__ w2n) {
    int j = threadIdx.x;  // 128 threads
    float ns = 0.f;
    for (int k = 0; k < 128; ++k) { float v = w1v[j * 128 + k]; ns += v * v; }
    float s = w1g[j] / sqrtf(ns);
    for (int k = 0; k < 128; ++k) W1n[j * 128 + k] = w1v[j * 128 + k] * s;
    float n2 = 0.f;
    for (int k = 0; k < 128; ++k) { float v = w2v[k]; n2 += v * v; }
    w2n[j] = w2v[j] * (w2g[0] / sqrtf(n2));
}

#define T_PAIRS (3 * 64 * 64)   // 12288 half2 = 48 KiB
#define W_PAIRS (128 * 64)      // 8192 half2  = 32 KiB

__launch_bounds__(512)
__global__ void mlp_main(const float* __restrict__ xyz,
                         const float* __restrict__ Tg,
                         const float* __restrict__ W1g,
                         const float* __restrict__ w2ng,
                         const float* __restrict__ b1,
                         const float* __restrict__ b2p,
                         float* __restrict__ out, int npts) {
    // T rows swizzled: pair p of row l stored at p^(l&63) -> bank = p&31 ^ l&31,
    // so the data-dependent row gather (uniform p, random l) is ~2-way (free).
    __shared__ h2 tT[T_PAIRS];
    __shared__ h2 tW[W_PAIRS];
    int tid = threadIdx.x;

    for (int u = tid; u < T_PAIRS; u += 512) {
        int l = (u >> 6) & 63;
        int p = u & 63;
        h2 v;
        v.x = (_Float16)Tg[2 * u];
        v.y = (_Float16)Tg[2 * u + 1];
        tT[(u & ~63) | (p ^ l)] = v;
    }
    for (int u = tid; u < W_PAIRS; u += 512) {
        h2 v;
        v.x = (_Float16)W1g[2 * u];
        v.y = (_Float16)W1g[2 * u + 1];
        tW[u] = v;
    }
    __syncthreads();

    float b2 = b2p[0];
    int stride = 512 * gridDim.x;
#pragma unroll 1
    for (int idx = blockIdx.x * 512 + tid; idx < npts; idx += stride) {
        float px = xyz[idx * 3 + 0];
        float py = xyz[idx * 3 + 1];
        float pz = xyz[idx * 3 + 2];

        h2 h[64];  // 64 f16x2 accumulators: fits the 128-VGPR budget

#pragma unroll
        for (int a = 0; a < 3; ++a) {
            float v = (a == 0) ? px : (a == 1) ? py : pz;
            v = fminf(fmaxf(v, 0.f), 1.f) * 63.f;
            float fv = floorf(v);
            int li = (int)fv;
            int ri = min(li + 1, 63);
            _Float16 w = (_Float16)(v - fv);
            _Float16 wl = (_Float16)1.0f - w;
            h2 wp = {w, w};
            h2 wlp = {wl, wl};
            const h2* rowL = &tT[(a * 64 + li) * 64];
            const h2* rowR = &tT[(a * 64 + ri) * 64];
            int sl = li & 63;
            int sr = ri & 63;
#pragma unroll
            for (int p = 0; p < 64; ++p) {
                h2 vl = rowL[p ^ sl];
                h2 vr = rowR[p ^ sr];
                if (a == 0)
                    h[p] = vl * wlp + vr * wp;
                else
                    h[p] = h[p] + vl * wlp + vr * wp;
            }
        }
        h2 zz = {(_Float16)0.f, (_Float16)0.f};
#pragma unroll
        for (int p = 0; p < 64; ++p)
            h[p] = __builtin_elementwise_max(h[p], zz);  // v_pk_max_f16

        float acc = b2;
#pragma unroll 1
        for (int jo = 0; jo < 128; jo += 8) {
            float s[8];
#pragma unroll
            for (int jj = 0; jj < 8; ++jj) s[jj] = b1[jo + jj];
#pragma unroll
            for (int kq = 0; kq < 16; ++kq) {
#pragma unroll
                for (int jj = 0; jj < 8; ++jj) {
                    const h2* wr = &tW[(jo + jj) * 64 + kq * 4];  // 16B -> b128
                    s[jj] = DOT2(h[kq * 4 + 0], wr[0], s[jj]);
                    s[jj] = DOT2(h[kq * 4 + 1], wr[1], s[jj]);
                    s[jj] = DOT2(h[kq * 4 + 2], wr[2], s[jj]);
                    s[jj] = DOT2(h[kq * 4 + 3], wr[3], s[jj]);
                }
            }
#pragma unroll
            for (int jj = 0; jj < 8; ++jj)
                acc += w2ng[jo + jj] * fmaxf(s[jj], 0.f);
        }
        out[idx] = acc;
    }
}

extern "C" void kernel_launch(void* const* d_in, const int* in_sizes, int n_in,
                              void* d_out, int out_size, void* d_ws, size_t ws_size,
                              hipStream_t stream) {
    const float* expr = (const float*)d_in[0];
    const float* jqw  = (const float*)d_in[1];
    const float* xyz  = (const float*)d_in[2];
    const float* flx  = (const float*)d_in[3];
    const float* fly  = (const float*)d_in[4];
    const float* flz  = (const float*)d_in[5];
    const float* w0v  = (const float*)d_in[6];
    const float* w0g  = (const float*)d_in[7];
    const float* b0   = (const float*)d_in[8];
    const float* w1v  = (const float*)d_in[9];
    const float* w1g  = (const float*)d_in[10];
    const float* b1   = (const float*)d_in[11];
    const float* w2v  = (const float*)d_in[12];
    const float* w2g  = (const float*)d_in[13];
    const float* b2   = (const float*)d_in[14];

    float* ws = (float*)d_ws;
    float* T   = ws;            // 24576 floats
    float* W1n = ws + 24576;    // 16384 floats
    float* w2n = ws + 40960;    // 128 floats

    int npts = in_sizes[2] / 3;

    precompute_T<<<192, 128, 0, stream>>>(expr, jqw, flx, fly, flz, w0v, w0g, b0, T);
    precompute_W<<<1, 128, 0, stream>>>(w1v, w1g, w2v, w2g, W1n, w2n);
    mlp_main<<<512, 512, 0, stream>>>(xyz, T, W1n, w2n, b1, b2, (float*)d_out, npts);
}

// Round 5
// 254.721 us; speedup vs baseline: 6.8453x; 3.0988x over previous
//
#include <hip/hip_runtime.h>
#include <math.h>

typedef _Float16 h2 __attribute__((ext_vector_type(2)));
typedef _Float16 f16x8 __attribute__((ext_vector_type(8)));
typedef float f32x4 __attribute__((ext_vector_type(4)));

// ws layout (floats):
//   [0, 24576)     T tables [3][64][128] f32 (b0 folded into axis 0)
//   [24576, 40960) W1n [128][128] f32 (weight-normed)
//   [40960, 41088) w2n [128] f32 (weight-normed row * g2)

__global__ void precompute_T(const float* __restrict__ expr,
                             const float* __restrict__ jqw,
                             const float* __restrict__ flx,
                             const float* __restrict__ fly,
                             const float* __restrict__ flz,
                             const float* __restrict__ w0v,
                             const float* __restrict__ w0g,
                             const float* __restrict__ b0,
                             float* __restrict__ T) {
    int a = blockIdx.x >> 6;   // axis 0..2
    int l = blockIdx.x & 63;   // grid row 0..63
    const float* fl = (a == 0) ? flx : (a == 1) ? fly : flz;
    __shared__ float bs[32];
    __shared__ float jaw[32];
    int t = threadIdx.x;
    if (t < 32) {
        float s = 0.f;
        for (int i = 0; i < 80; ++i) s += expr[i] * fl[(i * 64 + l) * 32 + t];
        bs[t] = s;
    } else if (t < 64) {
        int c = t - 32;
        float s = 0.f;
        for (int i = 0; i < 16; ++i) s += jqw[i] * fl[((80 + i) * 64 + l) * 32 + c];
        jaw[c] = s;
    }
    __syncthreads();
    int j = t;  // 128 threads, one output channel each
    float ns = 0.f;
    for (int c = 0; c < 192; ++c) { float v = w0v[j * 192 + c]; ns += v * v; }
    float scale = w0g[j] / sqrtf(ns);
    float acc = 0.f;
    for (int c = 0; c < 32; ++c) acc += w0v[j * 192 + a * 32 + c] * bs[c];
    for (int c = 0; c < 32; ++c) acc += w0v[j * 192 + 96 + a * 32 + c] * jaw[c];
    acc *= scale;
    if (a == 0) acc += b0[j];
    T[(a * 64 + l) * 128 + j] = acc;
}

__global__ void precompute_W(const float* __restrict__ w1v,
                             const float* __restrict__ w1g,
                             const float* __restrict__ w2v,
                             const float* __restrict__ w2g,
                             float* __restrict__ W1n,
                             float* __restrict__ w2n) {
    int j = threadIdx.x;  // 128 threads
    float ns = 0.f;
    for (int k = 0; k < 128; ++k) { float v = w1v[j * 128 + k]; ns += v * v; }
    float s = w1g[j] / sqrtf(ns);
    for (int k = 0; k < 128; ++k) W1n[j * 128 + k] = w1v[j * 128 + k] * s;
    float n2 = 0.f;
    for (int k = 0; k < 128; ++k) { float v = w2v[k]; n2 += v * v; }
    w2n[j] = w2v[j] * (w2g[0] / sqrtf(n2));
}

#define LDS_T_H2 12288   // 3*64*128 f16 = 48 KiB
#define LDS_B_H2 8192    // 128*128 f16  = 32 KiB (B-fragment order)

// Each wave processes 16-point tiles via v_mfma_f32_16x16x32_f16:
//   A[m][k]: m = point (lane&15), lane holds k = (lane>>4)*8+0..7 per K-step.
//   B[k][n]: W1n^T staged in exact fragment order -> linear ds_read_b128.
//   C[m][n]: m = (lane>>4)*4+i, n = lane&15 (per N-tile).
__launch_bounds__(512)
__global__ void mlp_mfma(const float* __restrict__ xyz,
                         const float* __restrict__ Tg,
                         const float* __restrict__ W1g,
                         const float* __restrict__ w2ng,
                         const float* __restrict__ b1,
                         const float* __restrict__ b2p,
                         float* __restrict__ out, int npts) {
    __shared__ __align__(16) h2 tT[LDS_T_H2];
    __shared__ __align__(16) h2 tB[LDS_B_H2];
    int tid = threadIdx.x;

    // Stage T (f32 -> f16). Row r (256B = 16 chunks of 16B); chunk c stored at
    // c ^ (r&15): the data-dependent row-gather (fixed chunk, random row) then
    // spreads across 16 chunk slots -> ~2-way bank aliasing (free).
    for (int pi = tid; pi < LDS_T_H2; pi += 512) {
        int r = pi >> 6;        // row 0..191
        int p = pi & 63;        // h2 within row
        int phys = (r << 6) | (((p >> 2) ^ (r & 15)) << 2) | (p & 3);
        h2 v;
        v.x = (_Float16)Tg[2 * pi];
        v.y = (_Float16)Tg[2 * pi + 1];
        tT[phys] = v;
    }
    // Stage W1 as B-fragments: pair pi = ((kk*8+nt)*64 + lane)*4 + dp holds
    // B[k = kk*32+(lane>>4)*8+2dp + {0,1}][n = nt*16+(lane&15)] = W1n[n][k].
    for (int pi = tid; pi < LDS_B_H2; pi += 512) {
        int dp = pi & 3;
        int l  = (pi >> 2) & 63;
        int nt = (pi >> 8) & 7;
        int kk = (pi >> 11) & 3;
        int n = nt * 16 + (l & 15);
        int k = kk * 32 + (l >> 4) * 8 + 2 * dp;
        h2 v;
        v.x = (_Float16)W1g[n * 128 + k];
        v.y = (_Float16)W1g[n * 128 + k + 1];
        tB[pi] = v;
    }
    __syncthreads();

    int lane = tid & 63;
    int lp = lane & 15;   // point-within-tile (A rows / C cols)
    int lg = lane >> 4;   // k-chunk group
    int waveid = blockIdx.x * 8 + (tid >> 6);
    int nwaves = gridDim.x * 8;
    int ntiles = (npts + 15) >> 4;

    // per-lane epilogue constants: channels n = nt*16 + lp
    float b1r[8], w2r[8];
#pragma unroll
    for (int nt = 0; nt < 8; ++nt) {
        b1r[nt] = b1[nt * 16 + lp];
        w2r[nt] = w2ng[nt * 16 + lp];
    }
    float b2 = b2p[0];

#pragma unroll 1
    for (int tile = waveid; tile < ntiles; tile += nwaves) {
        int m0 = tile << 4;
        int p = m0 + lp;
        int pc = min(p, npts - 1);
        float cx = xyz[pc * 3 + 0];
        float cy = xyz[pc * 3 + 1];
        float cz = xyz[pc * 3 + 2];

        // Build A fragments: hA[kk] = relu(h0[point lp][kk*32 + lg*8 + 0..7])
        f16x8 hA[4];
#pragma unroll
        for (int kk = 0; kk < 4; ++kk)
            hA[kk] = (f16x8){0, 0, 0, 0, 0, 0, 0, 0};

#pragma unroll
        for (int a = 0; a < 3; ++a) {
            float v = (a == 0) ? cx : (a == 1) ? cy : cz;
            v = fminf(fmaxf(v, 0.f), 1.f) * 63.f;
            float fv = floorf(v);
            int li = (int)fv;
            int ri = min(li + 1, 63);
            _Float16 w = (_Float16)(v - fv);
            _Float16 wl = (_Float16)1.0f - w;
            f16x8 w8  = {w, w, w, w, w, w, w, w};
            f16x8 wl8 = {wl, wl, wl, wl, wl, wl, wl, wl};
            int rowL = (a * 64 + li) << 4;  // chunk base
            int rowR = (a * 64 + ri) << 4;
            int sl = li & 15;
            int sr = ri & 15;
#pragma unroll
            for (int kk = 0; kk < 4; ++kk) {
                int cidx = lg + 4 * kk;
                f16x8 vl = *reinterpret_cast<const f16x8*>(
                    &tT[(rowL + (cidx ^ sl)) << 2]);
                f16x8 vr = *reinterpret_cast<const f16x8*>(
                    &tT[(rowR + (cidx ^ sr)) << 2]);
                hA[kk] = hA[kk] + vl * wl8 + vr * w8;
            }
        }
        f16x8 z8 = (f16x8){0, 0, 0, 0, 0, 0, 0, 0};
#pragma unroll
        for (int kk = 0; kk < 4; ++kk)
            hA[kk] = __builtin_elementwise_max(hA[kk], z8);

        // Layer 1: 8 N-tiles x 4 K-steps of mfma_f32_16x16x32_f16
        f32x4 acc[8];
#pragma unroll
        for (int nt = 0; nt < 8; ++nt) acc[nt] = (f32x4){0.f, 0.f, 0.f, 0.f};

#pragma unroll
        for (int kk = 0; kk < 4; ++kk) {
#pragma unroll
            for (int nt = 0; nt < 8; ++nt) {
                f16x8 b = *reinterpret_cast<const f16x8*>(
                    &tB[(((kk * 8 + nt) << 6) | lane) << 2]);
                acc[nt] = __builtin_amdgcn_mfma_f32_16x16x32_f16(
                    hA[kk], b, acc[nt], 0, 0, 0);
            }
        }

        // Layer 2 + bias/relu epilogue. acc[nt][i] = h1pre[m = lg*4+i][n = nt*16+lp]
        float part0 = 0.f, part1 = 0.f, part2 = 0.f, part3 = 0.f;
#pragma unroll
        for (int nt = 0; nt < 8; ++nt) {
            part0 += w2r[nt] * fmaxf(acc[nt][0] + b1r[nt], 0.f);
            part1 += w2r[nt] * fmaxf(acc[nt][1] + b1r[nt], 0.f);
            part2 += w2r[nt] * fmaxf(acc[nt][2] + b1r[nt], 0.f);
            part3 += w2r[nt] * fmaxf(acc[nt][3] + b1r[nt], 0.f);
        }
        // reduce over the 16 lanes (lp bits 0..3) holding this point's channels
#pragma unroll
        for (int mask = 1; mask <= 8; mask <<= 1) {
            part0 += __shfl_xor(part0, mask, 64);
            part1 += __shfl_xor(part1, mask, 64);
            part2 += __shfl_xor(part2, mask, 64);
            part3 += __shfl_xor(part3, mask, 64);
        }
        int mbase = m0 + (lg << 2);
        if (lp == 0 && mbase + 0 < npts) out[mbase + 0] = part0 + b2;
        if (lp == 1 && mbase + 1 < npts) out[mbase + 1] = part1 + b2;
        if (lp == 2 && mbase + 2 < npts) out[mbase + 2] = part2 + b2;
        if (lp == 3 && mbase + 3 < npts) out[mbase + 3] = part3 + b2;
    }
}

extern "C" void kernel_launch(void* const* d_in, const int* in_sizes, int n_in,
                              void* d_out, int out_size, void* d_ws, size_t ws_size,
                              hipStream_t stream) {
    const float* expr = (const float*)d_in[0];
    const float* jqw  = (const float*)d_in[1];
    const float* xyz  = (const float*)d_in[2];
    const float* flx  = (const float*)d_in[3];
    const float* fly  = (const float*)d_in[4];
    const float* flz  = (const float*)d_in[5];
    const float* w0v  = (const float*)d_in[6];
    const float* w0g  = (const float*)d_in[7];
    const float* b0   = (const float*)d_in[8];
    const float* w1v  = (const float*)d_in[9];
    const float* w1g  = (const float*)d_in[10];
    const float* b1   = (const float*)d_in[11];
    const float* w2v  = (const float*)d_in[12];
    const float* w2g  = (const float*)d_in[13];
    const float* b2   = (const float*)d_in[14];

    float* ws = (float*)d_ws;
    float* T   = ws;            // 24576 floats
    float* W1n = ws + 24576;    // 16384 floats
    float* w2n = ws + 40960;    // 128 floats

    int npts = in_sizes[2] / 3;

    precompute_T<<<192, 128, 0, stream>>>(expr, jqw, flx, fly, flz, w0v, w0g, b0, T);
    precompute_W<<<1, 128, 0, stream>>>(w1v, w1g, w2v, w2g, W1n, w2n);
    mlp_mfma<<<512, 512, 0, stream>>>(xyz, T, W1n, w2n, b1, b2, (float*)d_out, npts);
}